// Round 1
// baseline (1693.860 us; speedup 1.0000x reference)
//
#include <hip/hip_runtime.h>
#include <hip/hip_bf16.h>

#define NT   21
#define SEQ  1024
#define DIM  3072
#define NH   24
#define HD   128
#define ENCD 768
#define NAK  32
#define LTOT (NT*SEQ)    /* 21504 */
#define MKV  (NT*NAK)    /* 672   */

typedef __bf16 bf16x8 __attribute__((ext_vector_type(8)));
typedef float  f32x4  __attribute__((ext_vector_type(4)));

__device__ __forceinline__ ushort f2bf_rne(float f) {
    unsigned int u = __float_as_uint(f);
    u += 0x7FFFu + ((u >> 16) & 1u);
    return (ushort)(u >> 16);
}
__device__ __forceinline__ float bf2f(ushort u) {
    return __uint_as_float(((unsigned int)u) << 16);
}

// ---------------------------------------------------------------- conversions
__global__ void cvt_kernel(const float* __restrict__ src, ushort* __restrict__ dst, int n4) {
    int i = blockIdx.x * blockDim.x + threadIdx.x;
    int stride = gridDim.x * blockDim.x;
    for (; i < n4; i += stride) {
        float4 v = ((const float4*)src)[i];
        ushort4 o;
        o.x = f2bf_rne(v.x); o.y = f2bf_rne(v.y);
        o.z = f2bf_rne(v.z); o.w = f2bf_rne(v.w);
        ((ushort4*)dst)[i] = o;
    }
}

// ---------------------------------------------------------------- min/max of the two attn-map rows
__global__ void minmax_kernel(const float* __restrict__ m, float* __restrict__ mm) {
    __shared__ float red[4][256];
    int tid = threadIdx.x;
    float mn0 = 3.4e38f, mx0 = -3.4e38f, mn1 = 3.4e38f, mx1 = -3.4e38f;
    for (int i = tid; i < LTOT; i += 256) {
        float a = m[i], b = m[LTOT + i];
        mn0 = fminf(mn0, a); mx0 = fmaxf(mx0, a);
        mn1 = fminf(mn1, b); mx1 = fmaxf(mx1, b);
    }
    red[0][tid] = mn0; red[1][tid] = mx0; red[2][tid] = mn1; red[3][tid] = mx1;
    __syncthreads();
    for (int s = 128; s > 0; s >>= 1) {
        if (tid < s) {
            red[0][tid] = fminf(red[0][tid], red[0][tid + s]);
            red[1][tid] = fmaxf(red[1][tid], red[1][tid + s]);
            red[2][tid] = fminf(red[2][tid], red[2][tid + s]);
            red[3][tid] = fmaxf(red[3][tid], red[3][tid + s]);
        }
        __syncthreads();
    }
    if (tid == 0) { mm[0]=red[0][0]; mm[1]=red[1][0]; mm[2]=red[2][0]; mm[3]=red[3][0]; }
}

__global__ void pos_kernel(const float* __restrict__ m, const float* __restrict__ mm,
                           float* __restrict__ pos) {
    int i = blockIdx.x * 256 + threadIdx.x;
    if (i >= LTOT) return;
    float a = m[i], b = m[LTOT + i];
    float h1 = (a - mm[0]) * (4.0f / (mm[1] - mm[0]));               // [0,4]
    float h2 = (b - mm[2]) * (4.0f / (mm[3] - mm[2])) + 20.0f;       // [20,24]
    pos[i] = (a >= b) ? h1 : h2;   // argmax over 2 rows; 'back' row is unreachable
}

// ================================================================ 128^2 kernel (MODE 1: kv path only)
struct __align__(16) GemmSmem {
    union {
        ushort stage[2 * 128 * 64];  // A tile then B tile (16KB + 16KB)
        float  epi[64 * 133];        // half-tile epilogue buffer
    };
};

template <int MODE>
__global__ __launch_bounds__(256, 2) void gemm_bf16_kernel(
    const ushort* __restrict__ A, const ushort* __restrict__ W,
    const float* __restrict__ bias,
    const float* __restrict__ lng, const float* __restrict__ lnb,
    const float* __restrict__ pos,
    float* __restrict__ out0, float* __restrict__ kws, float* __restrict__ vws,
    int M, int K, int nTilesM, int nPerXcd)
{
    __shared__ GemmSmem sh;
    const int tid  = threadIdx.x;
    const int lane = tid & 63;
    const int wave = tid >> 6;
    const int wm = wave >> 1, wn = wave & 1;
    const int quad = lane >> 4, r16 = lane & 15;

    const int bid = blockIdx.x;
    const int xcd = bid & 7;
    const int j   = bid >> 3;
    const int mt  = j % nTilesM;
    const int nt  = xcd * nPerXcd + j / nTilesM;
    const int m0  = mt * 128;
    const int n0  = nt * 128;

    char* smA = (char*)sh.stage;          // 128 rows x 128 B
    char* smB = smA + 16384;

    f32x4 acc[4][4] = {};

    const int nK = K >> 6;   // BK = 64
    for (int kt = 0; kt < nK; ++kt) {
        const int k0 = kt << 6;
        __syncthreads();
        #pragma unroll
        for (int jj = 0; jj < 4; ++jj) {
            int slot = (wave * 4 + jj) * 64 + lane;
            int r  = slot >> 3;
            int c  = (slot & 7) ^ (r & 7);
            int row = m0 + r; if (row > M - 1) row = M - 1;
            const ushort* gp = A + (size_t)row * K + (k0 + c * 8);
            __builtin_amdgcn_global_load_lds(
                (const __attribute__((address_space(1))) void*)gp,
                (__attribute__((address_space(3))) void*)(smA + (wave * 4 + jj) * 1024),
                16, 0, 0);
        }
        #pragma unroll
        for (int jj = 0; jj < 4; ++jj) {
            int slot = (wave * 4 + jj) * 64 + lane;
            int r  = slot >> 3;
            int c  = (slot & 7) ^ (r & 7);
            const ushort* gp = W + (size_t)(n0 + r) * K + (k0 + c * 8);
            __builtin_amdgcn_global_load_lds(
                (const __attribute__((address_space(1))) void*)gp,
                (__attribute__((address_space(3))) void*)(smB + (wave * 4 + jj) * 1024),
                16, 0, 0);
        }
        __syncthreads();

        #pragma unroll
        for (int kk = 0; kk < 2; ++kk) {
            bf16x8 af[4], bfr[4];
            #pragma unroll
            for (int t = 0; t < 4; ++t) {
                int ra = wm * 64 + t * 16 + r16;
                af[t] = *(const bf16x8*)(smA + ra * 128 + ((((kk << 2) + quad) ^ (ra & 7)) << 4));
                int rb = wn * 64 + t * 16 + r16;
                bfr[t] = *(const bf16x8*)(smB + rb * 128 + ((((kk << 2) + quad) ^ (rb & 7)) << 4));
            }
            #pragma unroll
            for (int t = 0; t < 4; ++t)
                #pragma unroll
                for (int u = 0; u < 4; ++u)
                    acc[t][u] = __builtin_amdgcn_mfma_f32_16x16x32_bf16(af[t], bfr[u], acc[t][u], 0, 0, 0);
        }
    }

    const float inv128 = 1.0f / 128.0f;
    #pragma unroll
    for (int ph = 0; ph < 2; ++ph) {
        __syncthreads();
        if (wm == ph) {
            #pragma unroll
            for (int t = 0; t < 4; ++t)
                #pragma unroll
                for (int u = 0; u < 4; ++u)
                    #pragma unroll
                    for (int r = 0; r < 4; ++r) {
                        int ml = t * 16 + quad * 4 + r;
                        int nl = wn * 64 + u * 16 + r16;
                        sh.epi[ml * 133 + nl] = acc[t][u][r];
                    }
        }
        __syncthreads();
        if (tid < 64) {
            int gm = m0 + ph * 64 + tid;
            if (gm < M) {
                float* rowp = &sh.epi[tid * 133];
                int b = gm / NAK, n = gm - b * NAK;
                if (n0 < DIM) {     // k path: LN(1e-5) + RoPE(2/22), fp32
                    int head = n0 >> 7;
                    float pv = (n < 16) ? 2.0f : 22.0f;
                    float* op = kws + ((size_t)(b * NH + head) * NAK + n) * HD;
                    float s1 = 0.f, s2 = 0.f;
                    #pragma unroll 8
                    for (int jj = 0; jj < 128; ++jj) {
                        float val = rowp[jj] + bias[n0 + jj];
                        rowp[jj] = val;
                        s1 += val; s2 += val * val;
                    }
                    float mean = s1 * inv128;
                    float var  = s2 * inv128 - mean * mean;
                    float rinv = rsqrtf(var + 1e-5f);
                    #pragma unroll 4
                    for (int i = 0; i < 64; ++i) {
                        float x0 = (rowp[2 * i]     - mean) * rinv * lng[2 * i]     + lnb[2 * i];
                        float x1 = (rowp[2 * i + 1] - mean) * rinv * lng[2 * i + 1] + lnb[2 * i + 1];
                        float fr  = exp2f((float)i * -0.2076205059304601f);
                        float ang = pv * fr;
                        float sn = __sinf(ang), cs = __cosf(ang);
                        float2 o2;
                        o2.x = x0 * cs - x1 * sn;
                        o2.y = x1 * cs + x0 * sn;
                        *(float2*)(op + 2 * i) = o2;
                    }
                } else {            // v path: bias only, fp32
                    int head = (n0 - DIM) >> 7;
                    float* op = vws + ((size_t)(b * NH + head) * NAK + n) * HD;
                    #pragma unroll 8
                    for (int jj = 0; jj < 128; jj += 4) {
                        float4 b4 = *(const float4*)(bias + n0 + jj);
                        float4 v;
                        v.x = rowp[jj]     + b4.x;
                        v.y = rowp[jj + 1] + b4.y;
                        v.z = rowp[jj + 2] + b4.z;
                        v.w = rowp[jj + 3] + b4.w;
                        *(float4*)(op + jj) = v;
                    }
                }
            }
        }
    }
}

// ================================================================ 256^2 8-phase kernel (MODES 0 & 2)
// BM=BN=256, BK=64, 8 waves (2M x 4N), double-buffered 128 KiB LDS.
// Per K-tile: 4 quadrant phases, each {ds_read subtile || stage half-tile ->
// s_barrier -> lgkmcnt(0) -> setprio(1) -> 16 MFMA -> setprio(0) -> s_barrier}.
// Counted vmcnt(6) once per K-tile (3 half-tiles in flight); never drained to 0
// in the main loop. Staging placement is chosen so every global_load_lds into a
// region is issued only after a barrier that postdates all waves' completed
// ds_reads of that region (B halves: P3/P4; A h0: P4; A h1: next tile's P1).
struct __align__(16) Smem256 {
    union {
        ushort stage[65536];      // 2 bufs x (A 32KB + B 32KB) = 131072 B
        float  epi[64 * 260];     // 66,560 B epilogue band
    };
};

__device__ __forceinline__ void stage_half(const ushort* __restrict__ g, char* lds,
                                           int K, int wave, int lane) {
    // stages 128 rows x 64 bf16 (g points at row0,k0 of the half) with chunk-XOR swizzle
    #pragma unroll
    for (int jj = 0; jj < 2; ++jj) {
        int chunk = (wave * 2 + jj) * 64 + lane;   // 0..1023
        int r  = chunk >> 3;
        int cg = (chunk & 7) ^ (r & 7);
        const ushort* gp = g + (size_t)r * K + cg * 8;
        __builtin_amdgcn_global_load_lds(
            (const __attribute__((address_space(1))) void*)gp,
            (__attribute__((address_space(3))) void*)(lds + (wave * 2 + jj) * 1024),
            16, 0, 0);
    }
}

#define MID_SYNC() do { asm volatile("" ::: "memory"); __builtin_amdgcn_s_barrier(); \
    asm volatile("s_waitcnt lgkmcnt(0)" ::: "memory"); } while (0)
#define END_BAR() do { asm volatile("" ::: "memory"); __builtin_amdgcn_s_barrier(); \
    asm volatile("" ::: "memory"); } while (0)

template <int MODE>
__global__ __launch_bounds__(512, 2) void gemm256_kernel(
    const ushort* __restrict__ A, const ushort* __restrict__ W,
    const float* __restrict__ bias,
    const float* __restrict__ lng, const float* __restrict__ lnb,
    const float* __restrict__ pos,
    float* __restrict__ out0, int K, int nTilesM)
{
    __shared__ Smem256 sh;
    const int tid  = threadIdx.x;
    const int lane = tid & 63;
    const int wave = tid >> 6;
    const int wm = wave >> 2, wn = wave & 3;
    const int quad = lane >> 4, r16 = lane & 15;

    // bijective XCD swizzle (grid is a multiple of 8: 1008 = 8*126)
    const int cpx  = gridDim.x >> 3;
    const int bid  = blockIdx.x;
    const int wgid = (bid & 7) * cpx + (bid >> 3);
    const int mt = wgid % nTilesM;
    const int nt = wgid / nTilesM;
    const int m0 = mt << 8, n0 = nt << 8;

    const ushort* Ab = A + (size_t)m0 * K;
    const ushort* Bb = W + (size_t)n0 * K;
    char* smBase = (char*)sh.stage;

    f32x4 acc[8][4] = {};
    bf16x8 afr[4][2], b0f[2][2], b1f[2][2];

    const int nK = K >> 6;

    // -------- prologue: tile0 fully; tile1: B h0, B h1, A h0 (A h1 comes at t0-P1)
    {
        char* A0 = smBase;           char* B0 = smBase + 32768;
        char* A1 = smBase + 65536;   char* B1 = smBase + 98304;
        stage_half(Ab,                   A0,          K, wave, lane);
        stage_half(Ab + (size_t)128 * K, A0 + 16384,  K, wave, lane);
        stage_half(Bb,                   B0,          K, wave, lane);
        stage_half(Bb + (size_t)128 * K, B0 + 16384,  K, wave, lane);
        if (nK > 1) {
            stage_half(Bb + 64,                      B1,         K, wave, lane);
            stage_half(Bb + (size_t)128 * K + 64,    B1 + 16384, K, wave, lane);
            stage_half(Ab + 64,                      A1,         K, wave, lane);
            asm volatile("s_waitcnt vmcnt(6)" ::: "memory");
        } else {
            asm volatile("s_waitcnt vmcnt(0)" ::: "memory");
        }
        END_BAR();
    }

    for (int t = 0; t < nK; ++t) {
        const int cc = t & 1;
        char* smA  = smBase + cc * 65536;
        char* smB  = smA + 32768;
        char* smAo = smBase + (cc ^ 1) * 65536;
        const int k0n1 = (t + 1) << 6;
        const int k0n2 = (t + 2) << 6;

        // ---- P1: stage A_{t+1} h1 ; read A-sub0 + B-sub0 ; MFMA Q(0,0)
        if (t + 1 < nK)
            stage_half(Ab + (size_t)128 * K + k0n1, smAo + 16384, K, wave, lane);
        #pragma unroll
        for (int m = 0; m < 4; ++m) {
            int ra = wm * 128 + m * 16 + r16;
            #pragma unroll
            for (int kk = 0; kk < 2; ++kk)
                afr[m][kk] = *(const bf16x8*)(smA + ra * 128 + ((((kk << 2) + quad) ^ (ra & 7)) << 4));
        }
        #pragma unroll
        for (int n = 0; n < 2; ++n) {
            int rb = wn * 64 + n * 16 + r16;
            #pragma unroll
            for (int kk = 0; kk < 2; ++kk)
                b0f[n][kk] = *(const bf16x8*)(smB + rb * 128 + ((((kk << 2) + quad) ^ (rb & 7)) << 4));
        }
        MID_SYNC();
        __builtin_amdgcn_s_setprio(1);
        #pragma unroll
        for (int m = 0; m < 4; ++m)
            #pragma unroll
            for (int n = 0; n < 2; ++n)
                #pragma unroll
                for (int kk = 0; kk < 2; ++kk)
                    acc[m][n] = __builtin_amdgcn_mfma_f32_16x16x32_bf16(afr[m][kk], b0f[n][kk], acc[m][n], 0, 0, 0);
        __builtin_amdgcn_s_setprio(0);
        END_BAR();

        // ---- P2: read B-sub1 ; MFMA Q(0,1)
        #pragma unroll
        for (int n = 0; n < 2; ++n) {
            int rb = wn * 64 + (n + 2) * 16 + r16;
            #pragma unroll
            for (int kk = 0; kk < 2; ++kk)
                b1f[n][kk] = *(const bf16x8*)(smB + rb * 128 + ((((kk << 2) + quad) ^ (rb & 7)) << 4));
        }
        MID_SYNC();
        __builtin_amdgcn_s_setprio(1);
        #pragma unroll
        for (int m = 0; m < 4; ++m)
            #pragma unroll
            for (int n = 0; n < 2; ++n)
                #pragma unroll
                for (int kk = 0; kk < 2; ++kk)
                    acc[m][n + 2] = __builtin_amdgcn_mfma_f32_16x16x32_bf16(afr[m][kk], b1f[n][kk], acc[m][n + 2], 0, 0, 0);
        __builtin_amdgcn_s_setprio(0);
        END_BAR();

        // ---- P3: read A-sub1 ; stage B_{t+2} h0 ; MFMA Q(1,1)
        #pragma unroll
        for (int m = 0; m < 4; ++m) {
            int ra = wm * 128 + 64 + m * 16 + r16;
            #pragma unroll
            for (int kk = 0; kk < 2; ++kk)
                afr[m][kk] = *(const bf16x8*)(smA + ra * 128 + ((((kk << 2) + quad) ^ (ra & 7)) << 4));
        }
        if (t + 2 < nK)
            stage_half(Bb + k0n2, smB, K, wave, lane);
        MID_SYNC();
        __builtin_amdgcn_s_setprio(1);
        #pragma unroll
        for (int m = 0; m < 4; ++m)
            #pragma unroll
            for (int n = 0; n < 2; ++n)
                #pragma unroll
                for (int kk = 0; kk < 2; ++kk)
                    acc[m + 4][n + 2] = __builtin_amdgcn_mfma_f32_16x16x32_bf16(afr[m][kk], b1f[n][kk], acc[m + 4][n + 2], 0, 0, 0);
        __builtin_amdgcn_s_setprio(0);
        END_BAR();

        // ---- P4: stage B_{t+2} h1 + A_{t+2} h0 ; MFMA Q(1,0) ; counted vmcnt ; barrier
        if (t + 2 < nK) {
            stage_half(Bb + (size_t)128 * K + k0n2, smB + 16384, K, wave, lane);
            stage_half(Ab + k0n2,                   smA,         K, wave, lane);
        }
        __builtin_amdgcn_s_setprio(1);
        #pragma unroll
        for (int m = 0; m < 4; ++m)
            #pragma unroll
            for (int n = 0; n < 2; ++n)
                #pragma unroll
                for (int kk = 0; kk < 2; ++kk)
                    acc[m + 4][n] = __builtin_amdgcn_mfma_f32_16x16x32_bf16(afr[m][kk], b0f[n][kk], acc[m + 4][n], 0, 0, 0);
        __builtin_amdgcn_s_setprio(0);
        if (t + 2 < nK) asm volatile("s_waitcnt vmcnt(6)" ::: "memory");
        else            asm volatile("s_waitcnt vmcnt(0)" ::: "memory");
        END_BAR();
    }

    // -------- epilogue: 4 bands of 64 rows through LDS (all 512 threads active)
    const float inv128 = 1.0f / 128.0f;
    #pragma unroll
    for (int band = 0; band < 4; ++band) {
        if (wm == (band >> 1)) {
            const int mb = (band & 1) * 4;
            #pragma unroll
            for (int mm_ = 0; mm_ < 4; ++mm_)
                #pragma unroll
                for (int n = 0; n < 4; ++n)
                    #pragma unroll
                    for (int r = 0; r < 4; ++r)
                        sh.epi[(mm_ * 16 + quad * 4 + r) * 260 + wn * 64 + n * 16 + r16] = acc[mb + mm_][n][r];
        }
        END_BAR();
        if (MODE == 2) {
            int row = tid >> 3;
            int c8  = (tid & 7) * 4;
            int gm  = m0 + band * 64 + row;
            const float* rowp = sh.epi + row * 260;
            float* op = out0 + (size_t)gm * DIM + n0;
            #pragma unroll
            for (int jj = 0; jj < 8; ++jj) {
                int c = c8 + jj * 32;
                float4 b4 = *(const float4*)(bias + n0 + c);
                float4 v;
                v.x = rowp[c]     + b4.x;
                v.y = rowp[c + 1] + b4.y;
                v.z = rowp[c + 2] + b4.z;
                v.w = rowp[c + 3] + b4.w;
                *(float4*)(op + c) = v;
            }
        } else {
            // MODE 0: q path, LN(1e-6) + RoPE -> bf16 [b,h,s,d]; 4 threads per row-head
            int rh  = tid >> 2, sub = tid & 3;
            int row = rh >> 1, hl = rh & 1;
            int gm  = m0 + band * 64 + row;
            const float* rowp = sh.epi + row * 260 + hl * 128;
            const float* bp   = bias + n0 + hl * 128;
            float s1 = 0.f, s2 = 0.f;
            #pragma unroll
            for (int jj = 0; jj < 32; ++jj) {
                float v = rowp[sub + jj * 4] + bp[sub + jj * 4];
                s1 += v; s2 += v * v;
            }
            s1 += __shfl_xor(s1, 1); s2 += __shfl_xor(s2, 1);
            s1 += __shfl_xor(s1, 2); s2 += __shfl_xor(s2, 2);
            float mean = s1 * inv128;
            float var  = s2 * inv128 - mean * mean;
            float rinv = rsqrtf(var + 1e-6f);
            int b = gm >> 10, s = gm & 1023;
            int head = (n0 >> 7) + hl;
            int leff = ((b * NH + head) * SEQ + s) % LTOT;   // bug-faithful flat reshape
            float pv = pos[leff];
            ushort* opq = (ushort*)out0 + ((size_t)(b * NH + head) * SEQ + s) * HD;
            #pragma unroll
            for (int ii = 0; ii < 16; ++ii) {
                int i = sub + ii * 4;
                float x0 = (rowp[2 * i]     + bp[2 * i]     - mean) * rinv * lng[2 * i]     + lnb[2 * i];
                float x1 = (rowp[2 * i + 1] + bp[2 * i + 1] - mean) * rinv * lng[2 * i + 1] + lnb[2 * i + 1];
                float fr  = exp2f((float)i * -0.2076205059304601f); // 10000^(-2i/128)
                float ang = pv * fr;
                float sn = __sinf(ang), cs = __cosf(ang);
                ushort2 o2;
                o2.x = f2bf_rne(x0 * cs - x1 * sn);
                o2.y = f2bf_rne(x1 * cs + x0 * sn);
                *(ushort2*)(opq + 2 * i) = o2;
            }
        }
        END_BAR();
    }
}

// ---------------------------------------------------------------- attention (N=32 keys), fp32 vector, bf16 q
__global__ __launch_bounds__(256) void attn_kernel(
    const ushort* __restrict__ q, const float* __restrict__ kws,
    const float* __restrict__ vws, ushort* __restrict__ obf)
{
    __shared__ float ks[NAK * HD];
    __shared__ float vs[NAK * HD];
    int tid  = threadIdx.x;
    int bh   = blockIdx.x >> 2;
    int sblk = blockIdx.x & 3;
    const float4* kg = (const float4*)(kws + (size_t)bh * NAK * HD);
    const float4* vg = (const float4*)(vws + (size_t)bh * NAK * HD);
    for (int i = tid; i < NAK * HD / 4; i += 256) {
        ((float4*)ks)[i] = kg[i];
        ((float4*)vs)[i] = vg[i];
    }
    __syncthreads();

    int s_tok = sblk * 256 + tid;
    const ushort* qp = q + ((size_t)bh * SEQ + s_tok) * HD;

    float sc[NAK];
    #pragma unroll
    for (int n = 0; n < NAK; ++n) sc[n] = 0.f;

    for (int dc = 0; dc < HD; dc += 32) {
        float qc[32];
        #pragma unroll
        for (int jj = 0; jj < 8; ++jj) {
            ushort4 u4 = *(const ushort4*)(qp + dc + jj * 4);
            qc[jj*4]   = bf2f(u4.x); qc[jj*4+1] = bf2f(u4.y);
            qc[jj*4+2] = bf2f(u4.z); qc[jj*4+3] = bf2f(u4.w);
        }
        #pragma unroll
        for (int n = 0; n < NAK; ++n) {
            const float* kr = ks + n * HD + dc;
            float a0 = 0.f;
            #pragma unroll
            for (int jj = 0; jj < 8; ++jj) {
                float4 k4 = *(const float4*)(kr + jj * 4);
                a0 += qc[jj*4]*k4.x + qc[jj*4+1]*k4.y + qc[jj*4+2]*k4.z + qc[jj*4+3]*k4.w;
            }
            sc[n] += a0;
        }
    }
    const float scale = 0.08838834764831845f;  // 128^-0.5
    float mx = -3.4e38f;
    #pragma unroll
    for (int n = 0; n < NAK; ++n) { sc[n] *= scale; mx = fmaxf(mx, sc[n]); }
    float sum = 0.f;
    #pragma unroll
    for (int n = 0; n < NAK; ++n) { sc[n] = __expf(sc[n] - mx); sum += sc[n]; }
    float inv = 1.0f / sum;
    #pragma unroll
    for (int n = 0; n < NAK; ++n) sc[n] *= inv;

    int b = bh / NH, h = bh - b * NH;
    ushort* op = obf + ((size_t)(b * SEQ + s_tok)) * DIM + h * HD;
    for (int dc = 0; dc < HD; dc += 32) {
        float oc[32];
        #pragma unroll
        for (int jj = 0; jj < 32; ++jj) oc[jj] = 0.f;
        #pragma unroll
        for (int n = 0; n < NAK; ++n) {
            float pn = sc[n];
            const float* vr = vs + n * HD + dc;
            #pragma unroll
            for (int jj = 0; jj < 8; ++jj) {
                float4 v4 = *(const float4*)(vr + jj * 4);
                oc[jj*4]   += pn * v4.x; oc[jj*4+1] += pn * v4.y;
                oc[jj*4+2] += pn * v4.z; oc[jj*4+3] += pn * v4.w;
            }
        }
        #pragma unroll
        for (int jj = 0; jj < 8; ++jj) {
            ushort4 o4;
            o4.x = f2bf_rne(oc[jj*4]);   o4.y = f2bf_rne(oc[jj*4+1]);
            o4.z = f2bf_rne(oc[jj*4+2]); o4.w = f2bf_rne(oc[jj*4+3]);
            *(ushort4*)(op + dc + jj * 4) = o4;
        }
    }
}

// ---------------------------------------------------------------- launch
extern "C" void kernel_launch(void* const* d_in, const int* in_sizes, int n_in,
                              void* d_out, int out_size, void* d_ws, size_t ws_size,
                              hipStream_t stream) {
    const float* x    = (const float*)d_in[0];
    const float* enc  = (const float*)d_in[1];
    const float* amap = (const float*)d_in[2];
    const float* q_w  = (const float*)d_in[3];
    const float* q_b  = (const float*)d_in[4];
    const float* kv_w = (const float*)d_in[5];
    const float* kv_b = (const float*)d_in[6];
    const float* p_w  = (const float*)d_in[7];
    const float* p_b  = (const float*)d_in[8];
    const float* qn_g = (const float*)d_in[9];
    const float* qn_b = (const float*)d_in[10];
    const float* kn_g = (const float*)d_in[11];
    const float* kn_b = (const float*)d_in[12];
    float* out = (float*)d_out;

    char* ws = (char*)d_ws;
    ushort* x_bf   = (ushort*)(ws);                    // 132,120,576
    ushort* qw_bf  = (ushort*)(ws + 132120576);        //  18,874,368
    ushort* pw_bf  = (ushort*)(ws + 150994944);        //  18,874,368
    ushort* enc_bf = (ushort*)(ws + 169869312);        //   1,032,192
    ushort* kvw_bf = (ushort*)(ws + 170901504);        //   9,437,184
    float*  k_ws   = (float*)(ws + 180338688);         //   8,257,536
    float*  v_ws   = (float*)(ws + 188596224);         //   8,257,536
    float*  pos    = (float*)(ws + 196853760);         //      86,016
    float*  mm     = (float*)(ws + 196939776);         //          16

    cvt_kernel<<<1024, 256, 0, stream>>>(x,    x_bf,   66060288 / 4);
    cvt_kernel<<<256,  256, 0, stream>>>(q_w,  qw_bf,  9437184 / 4);
    cvt_kernel<<<256,  256, 0, stream>>>(p_w,  pw_bf,  9437184 / 4);
    cvt_kernel<<<64,   256, 0, stream>>>(enc,  enc_bf, 516096 / 4);
    cvt_kernel<<<128,  256, 0, stream>>>(kv_w, kvw_bf, 4718592 / 4);

    minmax_kernel<<<1, 256, 0, stream>>>(amap, mm);
    pos_kernel<<<84, 256, 0, stream>>>(amap, mm, pos);

    // KV projection + k-norm + k-rope (128^2 kernel): 48 n-tiles x 6 m-tiles
    gemm_bf16_kernel<1><<<288, 256, 0, stream>>>(
        enc_bf, kvw_bf, kv_b, kn_g, kn_b, nullptr, nullptr, k_ws, v_ws, MKV, ENCD, 6, 6);

    // Q projection + q-norm + rope (256^2 8-phase): 84 m-tiles x 12 n-tiles = 1008 blocks
    gemm256_kernel<0><<<1008, 512, 0, stream>>>(
        x_bf, qw_bf, q_b, qn_g, qn_b, pos, out, DIM, 84);

    // attention: reads q (bf16) from d_out, writes o (bf16) into x_bf region
    attn_kernel<<<NT * NH * 4, 256, 0, stream>>>((const ushort*)out, k_ws, v_ws, x_bf);

    // output projection (256^2 8-phase) -> final fp32 in d_out
    gemm256_kernel<2><<<1008, 512, 0, stream>>>(
        x_bf, pw_bf, p_b, nullptr, nullptr, nullptr, out, DIM, 84);
}